// Round 1
// baseline (12.192 us; speedup 1.0000x reference)
//
#include <hip/hip_runtime.h>

// VGG3_Test_B — analytic collapse.
//
// The reference network's every stage ends with relu -> binarize, and
// binarize(relu(z)) == +1 for ALL z (relu >= 0; binarize maps [0,inf) -> +1).
// Hence:
//   block1 output ≡ ones, block2 output ≡ ones, block3 output ≡ ones,
//   final: out[b] = (sign(wf2[0]) + bf2[0]) * scale[0]  for every sample b.
// The whole op is a constant broadcast into d_out ([B,1] float32).
//
// Input order (setup_inputs): 0:x 1:w1 2:b1 3:g1 4:be1 5:w2 6:b2 7:g2 8:be2
//                             9:wf1 10:bf1 11:g3 12:be3 13:wf2 14:bf2 15:scale

__global__ void vgg3_const_fill(const float* __restrict__ wf2,
                                const float* __restrict__ bf2,
                                const float* __restrict__ scale,
                                float* __restrict__ out, int n) {
    // Compute the constant on-device (3 scalar loads hit L2/L3; negligible).
    const float sgn = (wf2[0] >= 0.0f) ? 1.0f : -1.0f;
    const float c = (sgn + bf2[0]) * scale[0];

    int i = (blockIdx.x * blockDim.x + threadIdx.x) * 4;
    if (i + 3 < n) {
        *reinterpret_cast<float4*>(out + i) = make_float4(c, c, c, c);
    } else {
        for (int j = i; j < n; ++j) out[j] = c;
    }
}

extern "C" void kernel_launch(void* const* d_in, const int* in_sizes, int n_in,
                              void* d_out, int out_size, void* d_ws, size_t ws_size,
                              hipStream_t stream) {
    const float* wf2   = (const float*)d_in[13];
    const float* bf2   = (const float*)d_in[14];
    const float* scale = (const float*)d_in[15];
    float* out = (float*)d_out;

    const int block = 256;
    const int elems_per_thread = 4;
    const int threads_needed = (out_size + elems_per_thread - 1) / elems_per_thread;
    const int grid = (threads_needed + block - 1) / block;

    vgg3_const_fill<<<grid, block, 0, stream>>>(wf2, bf2, scale, out, out_size);
}